// Round 1
// baseline (80.902 us; speedup 1.0000x reference)
//
#include <hip/hip_runtime.h>

// One wave (64 lanes) per output segment. Lane l owns dim l (DIM == 64).
// segment_ids is sorted, so segment s's ids are the contiguous range
// [lower_bound(seg, s), lower_bound(seg, s+1)). Two binary searches per
// wave (redundant across lanes -> effectively scalar), then a shfl-broadcast
// accumulation loop with coalesced 256B row reads.

#define DIM 64

__global__ __launch_bounds__(256) void emb_seg_sum_kernel(
    const float* __restrict__ params,
    const int*   __restrict__ ids,
    const int*   __restrict__ seg,
    float*       __restrict__ out,
    int n_ids, int num_segments)
{
    const int gtid = blockIdx.x * blockDim.x + threadIdx.x;
    const int wave = gtid >> 6;
    const int lane = threadIdx.x & 63;
    if (wave >= num_segments) return;

    // lower_bound(seg, wave)
    int lo = 0, hi = n_ids;
    while (lo < hi) {
        int mid = (lo + hi) >> 1;
        if (seg[mid] < wave) lo = mid + 1; else hi = mid;
    }
    const int start = lo;
    // lower_bound(seg, wave + 1)  (start from `start`)
    hi = n_ids;
    while (lo < hi) {
        int mid = (lo + hi) >> 1;
        if (seg[mid] <= wave) lo = mid + 1; else hi = mid;
    }
    const int end = lo;

    float acc = 0.0f;
    for (int base = start; base < end; base += 64) {
        const int cnt = min(64, end - base);
        // Coalesced preload of up to 64 ids for this segment chunk.
        int myid = 0;
        if (base + lane < end) myid = ids[base + lane];
        for (int j = 0; j < cnt; ++j) {
            const int id = __shfl(myid, j);
            acc += params[(long long)id * DIM + lane];
        }
    }
    out[(long long)wave * DIM + lane] = acc;
}

extern "C" void kernel_launch(void* const* d_in, const int* in_sizes, int n_in,
                              void* d_out, int out_size, void* d_ws, size_t ws_size,
                              hipStream_t stream)
{
    const float* params = (const float*)d_in[0];
    const int*   ids    = (const int*)d_in[1];
    const int*   seg    = (const int*)d_in[2];
    float*       out    = (float*)d_out;

    const int n_ids        = in_sizes[1];
    const int num_segments = out_size / DIM;

    const int threads = 256;                       // 4 waves per block
    const int waves_per_block = threads / 64;
    const int grid = (num_segments + waves_per_block - 1) / waves_per_block;

    emb_seg_sum_kernel<<<grid, threads, 0, stream>>>(
        params, ids, seg, out, n_ids, num_segments);
}

// Round 2
// 45.626 us; speedup vs baseline: 1.7732x; 1.7732x over previous
//
#include <hip/hip_runtime.h>

#define DIM 64

__device__ __forceinline__ void f4acc(float4& a, const float4& v) {
    a.x += v.x; a.y += v.y; a.z += v.z; a.w += v.w;
}

// Kernel 1: offsets[s] = lower_bound(seg, s) for s in [0, num_segments].
// segment_ids is sorted, so each thread i marks the boundary gap (seg[i-1], seg[i]].
__global__ void seg_offsets_kernel(const int* __restrict__ seg, int* __restrict__ offsets,
                                   int n_ids, int num_segments)
{
    int i = blockIdx.x * blockDim.x + threadIdx.x;
    if (i >= n_ids) return;
    int cur  = seg[i];
    int prev = (i == 0) ? -1 : seg[i - 1];
    for (int s = prev + 1; s <= cur; ++s) offsets[s] = i;
    if (i == n_ids - 1) {
        for (int s = cur + 1; s <= num_segments; ++s) offsets[s] = n_ids;
    }
}

// Gather + segment-sum. One wave per segment.
// Lane layout: sub = lane>>4 selects row-within-group-of-4, col4 = lane&15 selects
// the float4 column. One load instruction = 64 lanes x 16B = 1KB = 4 full rows.
// 4 groups (16 rows) per iteration with independent accumulators for MLP.
template <bool USE_OFFSETS>
__global__ __launch_bounds__(256) void emb_seg_sum_kernel(
    const float* __restrict__ params,
    const int*   __restrict__ ids,
    const int*   __restrict__ seg_or_off,
    float*       __restrict__ out,
    int n_ids, int num_segments)
{
    const int gtid = blockIdx.x * blockDim.x + threadIdx.x;
    const int wseg = gtid >> 6;
    const int lane = threadIdx.x & 63;
    if (wseg >= num_segments) return;

    int start, end;
    if (USE_OFFSETS) {
        start = seg_or_off[wseg];
        end   = seg_or_off[wseg + 1];
    } else {
        // lower_bound(seg, wseg) and lower_bound(seg, wseg+1)
        int lo = 0, hi = n_ids;
        while (lo < hi) {
            int mid = (lo + hi) >> 1;
            if (seg_or_off[mid] < wseg) lo = mid + 1; else hi = mid;
        }
        start = lo;
        hi = n_ids;
        while (lo < hi) {
            int mid = (lo + hi) >> 1;
            if (seg_or_off[mid] <= wseg) lo = mid + 1; else hi = mid;
        }
        end = lo;
    }

    const int sub  = lane >> 4;       // which row of the group of 4
    const int col4 = lane & 15;       // float4 column within the row

    float4 a0 = {0,0,0,0}, a1 = {0,0,0,0}, a2 = {0,0,0,0}, a3 = {0,0,0,0};

    for (int base = start; base < end; base += 16) {
        const int r0 = base      + sub;
        const int r1 = base + 4  + sub;
        const int r2 = base + 8  + sub;
        const int r3 = base + 12 + sub;
        if (r0 < end) {
            int id = ids[r0];
            f4acc(a0, *(const float4*)(params + (size_t)id * DIM + col4 * 4));
        }
        if (r1 < end) {
            int id = ids[r1];
            f4acc(a1, *(const float4*)(params + (size_t)id * DIM + col4 * 4));
        }
        if (r2 < end) {
            int id = ids[r2];
            f4acc(a2, *(const float4*)(params + (size_t)id * DIM + col4 * 4));
        }
        if (r3 < end) {
            int id = ids[r3];
            f4acc(a3, *(const float4*)(params + (size_t)id * DIM + col4 * 4));
        }
    }

    f4acc(a0, a1); f4acc(a2, a3); f4acc(a0, a2);

    // Reduce across the 4 row-subsets (lane bits 4 and 5).
    a0.x += __shfl_xor(a0.x, 16); a0.y += __shfl_xor(a0.y, 16);
    a0.z += __shfl_xor(a0.z, 16); a0.w += __shfl_xor(a0.w, 16);
    a0.x += __shfl_xor(a0.x, 32); a0.y += __shfl_xor(a0.y, 32);
    a0.z += __shfl_xor(a0.z, 32); a0.w += __shfl_xor(a0.w, 32);

    if (lane < 16) {
        *(float4*)(out + (size_t)wseg * DIM + col4 * 4) = a0;
    }
}

extern "C" void kernel_launch(void* const* d_in, const int* in_sizes, int n_in,
                              void* d_out, int out_size, void* d_ws, size_t ws_size,
                              hipStream_t stream)
{
    const float* params = (const float*)d_in[0];
    const int*   ids    = (const int*)d_in[1];
    const int*   seg    = (const int*)d_in[2];
    float*       out    = (float*)d_out;

    const int n_ids        = in_sizes[1];
    const int num_segments = out_size / DIM;

    const int threads = 256;                        // 4 waves per block
    const int waves_per_block = threads / 64;
    const int grid = (num_segments + waves_per_block - 1) / waves_per_block;

    const size_t off_bytes = (size_t)(num_segments + 1) * sizeof(int);
    if (ws_size >= off_bytes) {
        int* offsets = (int*)d_ws;
        seg_offsets_kernel<<<(n_ids + 255) / 256, 256, 0, stream>>>(
            seg, offsets, n_ids, num_segments);
        emb_seg_sum_kernel<true><<<grid, threads, 0, stream>>>(
            params, ids, offsets, out, n_ids, num_segments);
    } else {
        emb_seg_sum_kernel<false><<<grid, threads, 0, stream>>>(
            params, ids, seg, out, n_ids, num_segments);
    }
}

// Round 3
// 42.157 us; speedup vs baseline: 1.9191x; 1.0823x over previous
//
#include <hip/hip_runtime.h>

#define DIM 64

__device__ __forceinline__ void f4acc(float4& a, const float4& v) {
    a.x += v.x; a.y += v.y; a.z += v.z; a.w += v.w;
}

// Kernel 1: offsets[s] = lower_bound(seg, s) for s in [0, num_segments].
// segment_ids is sorted, so each thread i marks the boundary gap (seg[i-1], seg[i]].
__global__ void seg_offsets_kernel(const int* __restrict__ seg, int* __restrict__ offsets,
                                   int n_ids, int num_segments)
{
    int i = blockIdx.x * blockDim.x + threadIdx.x;
    if (i >= n_ids) return;
    int cur  = seg[i];
    int prev = (i == 0) ? -1 : seg[i - 1];
    for (int s = prev + 1; s <= cur; ++s) offsets[s] = i;
    if (i == n_ids - 1) {
        for (int s = cur + 1; s <= num_segments; ++s) offsets[s] = n_ids;
    }
}

// Gather + segment-sum. One wave per segment.
// Lane layout: sub = lane>>4 picks the row within a group of 4, col4 = lane&15
// picks the float4 column. One gather instruction = 64 lanes x 16B = 4 full rows.
// ids for a 64-row chunk are preloaded with ONE coalesced lane-indexed load and
// redistributed via __shfl, keeping global ids loads off the gather critical path.
template <bool USE_OFFSETS>
__global__ __launch_bounds__(256) void emb_seg_sum_kernel(
    const float* __restrict__ params,
    const int*   __restrict__ ids,
    const int*   __restrict__ seg_or_off,
    float*       __restrict__ out,
    int n_ids, int num_segments)
{
    const int gtid = blockIdx.x * blockDim.x + threadIdx.x;
    const int wseg = gtid >> 6;
    const int lane = threadIdx.x & 63;
    if (wseg >= num_segments) return;

    int start, end;
    if (USE_OFFSETS) {
        start = seg_or_off[wseg];
        end   = seg_or_off[wseg + 1];
    } else {
        int lo = 0, hi = n_ids;
        while (lo < hi) {
            int mid = (lo + hi) >> 1;
            if (seg_or_off[mid] < wseg) lo = mid + 1; else hi = mid;
        }
        start = lo;
        hi = n_ids;
        while (lo < hi) {
            int mid = (lo + hi) >> 1;
            if (seg_or_off[mid] <= wseg) lo = mid + 1; else hi = mid;
        }
        end = lo;
    }

    const int sub  = lane >> 4;              // row within group-of-4
    const int col4 = lane & 15;              // float4 column
    const float* __restrict__ pcol = params + col4 * 4;

    float4 a0 = {0,0,0,0}, a1 = {0,0,0,0}, a2 = {0,0,0,0}, a3 = {0,0,0,0};

    for (int base = start; base < end; base += 64) {
        const int cnt = min(64, end - base);
        // One coalesced load covers this chunk's ids.
        int myid = 0;
        if (base + lane < end) myid = ids[base + lane];

        int j = 0;
        for (; j + 16 <= cnt; j += 16) {
            const int i0 = __shfl(myid, j      + sub);
            const int i1 = __shfl(myid, j + 4  + sub);
            const int i2 = __shfl(myid, j + 8  + sub);
            const int i3 = __shfl(myid, j + 12 + sub);
            const float4 v0 = *(const float4*)(pcol + (size_t)i0 * DIM);
            const float4 v1 = *(const float4*)(pcol + (size_t)i1 * DIM);
            const float4 v2 = *(const float4*)(pcol + (size_t)i2 * DIM);
            const float4 v3 = *(const float4*)(pcol + (size_t)i3 * DIM);
            f4acc(a0, v0); f4acc(a1, v1); f4acc(a2, v2); f4acc(a3, v3);
        }
        for (; j + 4 <= cnt; j += 4) {
            const int i0 = __shfl(myid, j + sub);
            f4acc(a1, *(const float4*)(pcol + (size_t)i0 * DIM));
        }
        if (j < cnt) {
            const int r  = j + sub;
            const int i0 = __shfl(myid, (r < cnt) ? r : j);
            if (r < cnt) {
                f4acc(a2, *(const float4*)(pcol + (size_t)i0 * DIM));
            }
        }
    }

    f4acc(a0, a1); f4acc(a2, a3); f4acc(a0, a2);

    // Reduce across the 4 row-subsets (lane bits 4 and 5).
    a0.x += __shfl_xor(a0.x, 16); a0.y += __shfl_xor(a0.y, 16);
    a0.z += __shfl_xor(a0.z, 16); a0.w += __shfl_xor(a0.w, 16);
    a0.x += __shfl_xor(a0.x, 32); a0.y += __shfl_xor(a0.y, 32);
    a0.z += __shfl_xor(a0.z, 32); a0.w += __shfl_xor(a0.w, 32);

    if (lane < 16) {
        *(float4*)(out + (size_t)wseg * DIM + col4 * 4) = a0;
    }
}

extern "C" void kernel_launch(void* const* d_in, const int* in_sizes, int n_in,
                              void* d_out, int out_size, void* d_ws, size_t ws_size,
                              hipStream_t stream)
{
    const float* params = (const float*)d_in[0];
    const int*   ids    = (const int*)d_in[1];
    const int*   seg    = (const int*)d_in[2];
    float*       out    = (float*)d_out;

    const int n_ids        = in_sizes[1];
    const int num_segments = out_size / DIM;

    const int threads = 256;                        // 4 waves per block
    const int waves_per_block = threads / 64;
    const int grid = (num_segments + waves_per_block - 1) / waves_per_block;

    const size_t off_bytes = (size_t)(num_segments + 1) * sizeof(int);
    if (ws_size >= off_bytes) {
        int* offsets = (int*)d_ws;
        seg_offsets_kernel<<<(n_ids + 255) / 256, 256, 0, stream>>>(
            seg, offsets, n_ids, num_segments);
        emb_seg_sum_kernel<true><<<grid, threads, 0, stream>>>(
            params, ids, offsets, out, n_ids, num_segments);
    } else {
        emb_seg_sum_kernel<false><<<grid, threads, 0, stream>>>(
            params, ids, seg, out, n_ids, num_segments);
    }
}